// Round 5
// baseline (644.574 us; speedup 1.0000x reference)
//
#include <hip/hip_runtime.h>
#include <hip/hip_bf16.h>
#include <stdint.h>

#define NTOK 49
#define CDIM 192
#define NHEADS 6

typedef __attribute__((ext_vector_type(8))) short bf16x8;
typedef __attribute__((ext_vector_type(4))) float f32x4;

// RNE float -> bf16 (bit trick)
__device__ __forceinline__ short f2b(float f) {
    uint32_t u = __float_as_uint(f);
    uint32_t r = (u + 0x7fffu + ((u >> 16) & 1u)) >> 16;
    return (short)r;
}

// Fast pack: 8 consecutive fp32 -> bf16x8
__device__ __forceinline__ bf16x8 cvt8(const float* p) {
    f32x4 a = *(const f32x4*)p;
    f32x4 b = *(const f32x4*)(p + 4);
    union { uint32_t u[4]; bf16x8 v; } r;
    uint32_t e0 = __float_as_uint(a[0]) + 0x8000u, e1 = __float_as_uint(a[1]) + 0x8000u;
    uint32_t e2 = __float_as_uint(a[2]) + 0x8000u, e3 = __float_as_uint(a[3]) + 0x8000u;
    uint32_t e4 = __float_as_uint(b[0]) + 0x8000u, e5 = __float_as_uint(b[1]) + 0x8000u;
    uint32_t e6 = __float_as_uint(b[2]) + 0x8000u, e7 = __float_as_uint(b[3]) + 0x8000u;
    r.u[0] = __builtin_amdgcn_perm(e1, e0, 0x07060302u);
    r.u[1] = __builtin_amdgcn_perm(e3, e2, 0x07060302u);
    r.u[2] = __builtin_amdgcn_perm(e5, e4, 0x07060302u);
    r.u[3] = __builtin_amdgcn_perm(e7, e6, 0x07060302u);
    return r.v;
}

// One-shot: transpose+cast qkv_w [192][576]f32 -> wt [576][192]bf16,
//           proj_w [192][192]f32 -> pwt [192][192]bf16
__global__ void transpose_w(const float* __restrict__ qkv_w,
                            const float* __restrict__ proj_w,
                            short* __restrict__ wt, short* __restrict__ pwt) {
    int idx = blockIdx.x * 256 + threadIdx.x;
    if (idx < CDIM * 3 * CDIM) {
        int c = idx / (3 * CDIM), j = idx % (3 * CDIM);
        wt[j * CDIM + c] = f2b(qkv_w[idx]);
    }
    if (idx < CDIM * CDIM) {
        int c = idx / CDIM, j = idx % CDIM;
        pwt[j * CDIM + c] = f2b(proj_w[idx]);
    }
}

// Fused window-attention, occupancy-targeted: 3 blocks/CU (12 waves/CU).
// LDS 44.2 KB; regs ~96 persistent (afr[2][6] + acco[3][4]); launch_bounds(256,3).
// QKV: wave = (jtile-half wv&1: 6 jtiles) x (mtile-half wv>>1: 2 mtiles).
// Attention: wave = (head wv&1, token-half wv>>1), mi sub-tiles SERIAL (r4 showed
//   softmax ILP is not the limiter; serializing halves Pbuf and live regs).
// Proj: per-pair K=64 accumulation into persistent acco.
__global__ __launch_bounds__(256, 3)
void winattn_kernel(const float* __restrict__ x, const float* __restrict__ mask,
                    const short* __restrict__ wt, const float* __restrict__ qkvb,
                    const short* __restrict__ pwt, const float* __restrict__ projb,
                    float* __restrict__ out) {
    // strides (dw mod 32): qbuf/kbuf 36sh=18dw; vtbuf/Pbuf 68sh=34dw(≡2); Obuf 66sh=33dw(≡1)
    __shared__ __align__(16) short qbuf[2][64][36];   //  9216 B [head][token][d]
    __shared__ __align__(16) short kbuf[2][64][36];   //  9216 B
    __shared__ __align__(16) short vtbuf[2][32][68];  //  8704 B [head][d][token]
    __shared__ __align__(16) short Pbuf[4][16][68];   //  8704 B per-wave P rows (one mi)
    __shared__ __align__(16) short Obuf[64][66];      //  8448 B pair O [token][paircol]

    const int b = blockIdx.x;
    const int tid = threadIdx.x;
    const int wv = tid >> 6;       // wave 0..3
    const int lane = tid & 63;
    const int q4 = lane >> 4;      // quad 0..3
    const int l16 = lane & 15;
    const int hl = wv & 1;         // attn: head within pair
    const int mh = wv >> 1;        // attn: token half; also QKV mtile-half
    const int jh = wv & 1;         // QKV: jtile half

    // ---- x A-frags: OWN mtile pair only (48 VGPRs) ----
    const float* xg = x + (size_t)b * NTOK * CDIM;
    bf16x8 zero = {};
    bf16x8 afr[2][6];
#pragma unroll
    for (int m = 0; m < 2; m++) {
        int n = (mh * 2 + m) * 16 + l16;
        const float* xr = xg + n * CDIM;
        bool valid = (n < NTOK);
#pragma unroll
        for (int ks = 0; ks < 6; ks++)
            afr[m][ks] = valid ? cvt8(xr + ks * 32 + q4 * 8) : zero;
    }

    const float* mg = mask + (size_t)(b & 63) * NTOK * NTOK;

    // ---- persistent proj accumulators: wave owns 3 col-tiles x 4 mtiles ----
    f32x4 acco[3][4];
#pragma unroll
    for (int a = 0; a < 3; a++)
#pragma unroll
        for (int m = 0; m < 4; m++) acco[a][m] = (f32x4){0.f, 0.f, 0.f, 0.f};

    const float SCALE = 0.17677669529663687f;

    for (int p = 0; p < 3; p++) {            // head pairs (2p, 2p+1)
        __syncthreads();                     // q/k/vt overwrite vs prior attn reads; Obuf vs proj reads

        // ================= QKV: 6 jtiles (own half) x 2 mtiles (own half) =================
#pragma unroll
        for (int t = 0; t < 6; t++) {
            int i = jh * 6 + t;
            int jt;
            if (i < 4)      jt = 4 * p + i;            // q cols
            else if (i < 8) jt = 12 + 4 * p + (i - 4); // k cols
            else            jt = 24 + 4 * p + (i - 8); // v cols
            int jb = jt * 16;
            const short* wrow = wt + (size_t)(jb + l16) * CDIM;
            bf16x8 bfr[6];
#pragma unroll
            for (int ks = 0; ks < 6; ks++)
                bfr[ks] = *(const bf16x8*)(wrow + ks * 32 + q4 * 8);
            f32x4 acc[2];
            acc[0] = (f32x4){0.f, 0.f, 0.f, 0.f};
            acc[1] = (f32x4){0.f, 0.f, 0.f, 0.f};
#pragma unroll
            for (int ks = 0; ks < 6; ks++)
#pragma unroll
                for (int m = 0; m < 2; m++)
                    acc[m] = __builtin_amdgcn_mfma_f32_16x16x32_bf16(afr[m][ks], bfr[ks], acc[m], 0, 0, 0);
            float bias = qkvb[jb + l16];
            int sect = jb / CDIM;            // 0=q 1=k 2=v
            int jm = jb % CDIM;
            int hw = (jm / 32) - 2 * p;      // head within pair
            int d = (jm % 32) + l16;
#pragma unroll
            for (int m = 0; m < 2; m++)
#pragma unroll
                for (int r = 0; r < 4; r++) {
                    int row = (mh * 2 + m) * 16 + q4 * 4 + r;
                    short v = f2b(acc[m][r] + bias);
                    if (sect == 0)      qbuf[hw][row][d] = v;
                    else if (sect == 1) kbuf[hw][row][d] = v;
                    else                vtbuf[hw][d][row] = v;
                }
        }
        __syncthreads();                     // K/V visible to all waves

        // ================= attention: head hl, rows mh*32..+31, mi SERIAL =================
#pragma unroll
        for (int mi = 0; mi < 2; mi++) {
            // premask (reloaded; mask region is L2/L3-hot and identical across pairs)
            float premask[4][4];
#pragma unroll
            for (int ct = 0; ct < 4; ct++)
#pragma unroll
                for (int r = 0; r < 4; r++) {
                    int row = mh * 32 + mi * 16 + q4 * 4 + r;
                    int col = ct * 16 + l16;
                    float mv = mg[min(row, 48) * NTOK + min(col, 48)];
                    premask[ct][r] = (row < NTOK && col < NTOK) ? mv : -1e30f;
                }
            // S = Q K^T
            bf16x8 qa = *(const bf16x8*)&qbuf[hl][mh * 32 + mi * 16 + l16][q4 * 8];
            f32x4 accs[4];
#pragma unroll
            for (int c = 0; c < 4; c++) accs[c] = (f32x4){0.f, 0.f, 0.f, 0.f};
#pragma unroll
            for (int ct = 0; ct < 4; ct++) {
                bf16x8 kb = *(const bf16x8*)&kbuf[hl][ct * 16 + l16][q4 * 8];
                accs[ct] = __builtin_amdgcn_mfma_f32_16x16x32_bf16(qa, kb, accs[ct], 0, 0, 0);
            }
            // softmax across 64 cols
            float s[4][4], mx[4], lsum[4];
#pragma unroll
            for (int r = 0; r < 4; r++) {
                mx[r] = -3.4e38f;
#pragma unroll
                for (int ct = 0; ct < 4; ct++) {
                    s[ct][r] = accs[ct][r] * SCALE + premask[ct][r];
                    mx[r] = fmaxf(mx[r], s[ct][r]);
                }
            }
#pragma unroll
            for (int w2 = 1; w2 < 16; w2 <<= 1)
#pragma unroll
                for (int r = 0; r < 4; r++) mx[r] = fmaxf(mx[r], __shfl_xor(mx[r], w2));
#pragma unroll
            for (int r = 0; r < 4; r++) lsum[r] = 0.f;
#pragma unroll
            for (int ct = 0; ct < 4; ct++)
#pragma unroll
                for (int r = 0; r < 4; r++) {
                    float e = __expf(s[ct][r] - mx[r]);
                    s[ct][r] = e;
                    lsum[r] += e;
                }
#pragma unroll
            for (int w2 = 1; w2 < 16; w2 <<= 1)
#pragma unroll
                for (int r = 0; r < 4; r++) lsum[r] += __shfl_xor(lsum[r], w2);
            // P -> wave-private LDS (C-layout -> A-layout), unnormalized
#pragma unroll
            for (int ct = 0; ct < 4; ct++)
#pragma unroll
                for (int r = 0; r < 4; r++)
                    Pbuf[wv][q4 * 4 + r][ct * 16 + l16] = f2b(s[ct][r]);
            // O = P V
            f32x4 accp[2];
            accp[0] = (f32x4){0.f, 0.f, 0.f, 0.f};
            accp[1] = (f32x4){0.f, 0.f, 0.f, 0.f};
#pragma unroll
            for (int ks = 0; ks < 2; ks++) {
                bf16x8 pa = *(const bf16x8*)&Pbuf[wv][l16][ks * 32 + q4 * 8];
#pragma unroll
                for (int jt2 = 0; jt2 < 2; jt2++) {
                    bf16x8 vb = *(const bf16x8*)&vtbuf[hl][jt2 * 16 + l16][ks * 32 + q4 * 8];
                    accp[jt2] = __builtin_amdgcn_mfma_f32_16x16x32_bf16(pa, vb, accp[jt2], 0, 0, 0);
                }
            }
            // normalize + write pair-Obuf (rows/cols disjoint across waves)
            float rl[4];
#pragma unroll
            for (int r = 0; r < 4; r++) rl[r] = 1.0f / lsum[r];
#pragma unroll
            for (int jt2 = 0; jt2 < 2; jt2++)
#pragma unroll
                for (int r = 0; r < 4; r++)
                    Obuf[mh * 32 + mi * 16 + q4 * 4 + r][hl * 32 + jt2 * 16 + l16] =
                        f2b(accp[jt2][r] * rl[r]);
        }
        __syncthreads();                     // pair O complete

        // ================= proj: accumulate this pair's K=64 slice =================
#pragma unroll
        for (int jtl = 0; jtl < 3; jtl++) {
            int jb = (wv * 3 + jtl) * 16;
            const short* wrow = pwt + (size_t)(jb + l16) * CDIM + p * 64;
            bf16x8 pb[2];
            pb[0] = *(const bf16x8*)(wrow + q4 * 8);
            pb[1] = *(const bf16x8*)(wrow + 32 + q4 * 8);
#pragma unroll
            for (int mt = 0; mt < 4; mt++) {
#pragma unroll
                for (int ks = 0; ks < 2; ks++) {
                    bf16x8 oa = *(const bf16x8*)&Obuf[mt * 16 + l16][ks * 32 + q4 * 8];
                    acco[jtl][mt] = __builtin_amdgcn_mfma_f32_16x16x32_bf16(oa, pb[ks], acco[jtl][mt], 0, 0, 0);
                }
            }
        }
    }

    // ---- epilogue: + proj bias, store FP32 ----
#pragma unroll
    for (int jtl = 0; jtl < 3; jtl++) {
        int jb = (wv * 3 + jtl) * 16;
        float bias = projb[jb + l16];
#pragma unroll
        for (int mt = 0; mt < 4; mt++)
#pragma unroll
            for (int r = 0; r < 4; r++) {
                int n = mt * 16 + q4 * 4 + r;
                if (n < NTOK)
                    out[((size_t)b * NTOK + n) * CDIM + jb + l16] = acco[jtl][mt][r] + bias;
            }
    }
}

extern "C" void kernel_launch(void* const* d_in, const int* in_sizes, int n_in,
                              void* d_out, int out_size, void* d_ws, size_t ws_size,
                              hipStream_t stream) {
    const float* x      = (const float*)d_in[0];
    const float* mask   = (const float*)d_in[1];
    const float* qkv_w  = (const float*)d_in[2];
    const float* qkv_b  = (const float*)d_in[3];
    const float* proj_w = (const float*)d_in[4];
    const float* proj_b = (const float*)d_in[5];
    short* wt  = (short*)d_ws;                 // [576][192] bf16
    short* pwt = wt + CDIM * 3 * CDIM;         // [192][192] bf16
    float* out = (float*)d_out;
    int B = in_sizes[0] / (NTOK * CDIM);       // 4096

    transpose_w<<<(CDIM * 3 * CDIM + 255) / 256, 256, 0, stream>>>(qkv_w, proj_w, wt, pwt);
    winattn_kernel<<<B, 256, 0, stream>>>(x, mask, wt, qkv_b, pwt, proj_b, out);
}